// Round 1
// baseline (229.615 us; speedup 1.0000x reference)
//
#include <hip/hip_runtime.h>
#include <hip/hip_bf16.h>
#include <math.h>

// Problem constants: B=64, SQ=64, SD=512, H=128
#define BB 64
#define SQN 64
#define SDN 512
#define HH 128
#define HP 136   // LDS row stride in shorts: 128 + 8 pad (272 B rows, 16B-aligned, breaks bank stride)

typedef __attribute__((ext_vector_type(8))) short frag_t;   // 8 bf16 = 4 VGPRs
typedef __attribute__((ext_vector_type(4))) float acc_t;    // 4 fp32 acc

__device__ __forceinline__ short f2bf(float f) {
  union { float f; unsigned u; } x; x.f = f;
  unsigned r = x.u + 0x7fffu + ((x.u >> 16) & 1u);   // RNE
  return (short)(r >> 16);
}

// scores[a][side*64+b] = sum_s max_{t: mask[b,t]} (q[a,s,:] . d[b,t,:])
__global__ __launch_bounds__(256)
void maxsim_kernel(const float* __restrict__ q,
                   const float* __restrict__ d_pos,
                   const float* __restrict__ d_neg,
                   const int* __restrict__ mask_pos,
                   const int* __restrict__ mask_neg,
                   float* __restrict__ scores) {
  const int a = blockIdx.x;     // x fastest-varying -> consecutive blocks share b (L2 d-reuse)
  const int b = blockIdx.y;
  const int side = blockIdx.z;
  const float* dmat = side ? d_neg : d_pos;
  const int* mask   = side ? mask_neg : mask_pos;

  __shared__ short q_lds[SQN * HP];    // 17408 B
  __shared__ short d_lds[128 * HP];    // 34816 B
  __shared__ int   m_lds[128];
  __shared__ float red[4];

  const int tid  = threadIdx.x;
  const int lane = tid & 63;
  const int wave = tid >> 6;
  const int col  = lane & 15;   // N index in C; row index for A/B fragment loads
  const int quad = lane >> 4;   // selects k-offset (quad*8) in A/B frags; row group in C

  // ---- stage q[a]: 64x128 fp32 -> bf16 LDS ----
  {
    const float4* src = (const float4*)(q + (size_t)a * SQN * HH);
    #pragma unroll
    for (int it = 0; it < (SQN * HH / 4) / 256; ++it) {   // 8 iters
      int idx4 = it * 256 + tid;
      float4 v = src[idx4];
      int idx = idx4 * 4;
      int r = idx >> 7, c = idx & 127;
      short4 o;
      o.x = f2bf(v.x); o.y = f2bf(v.y); o.z = f2bf(v.z); o.w = f2bf(v.w);
      *(short4*)&q_lds[r * HP + c] = o;
    }
  }
  __syncthreads();

  // preload this wave's A fragments (s-tile = wave*16 .. +16), K=128 in 4 chunks of 32
  frag_t afrag[4];
  #pragma unroll
  for (int kc = 0; kc < 4; ++kc)
    afrag[kc] = *(const frag_t*)&q_lds[(wave * 16 + col) * HP + kc * 32 + quad * 8];

  float rmax0 = -INFINITY, rmax1 = -INFINITY, rmax2 = -INFINITY, rmax3 = -INFINITY;

  for (int tc = 0; tc < SDN / 128; ++tc) {
    // ---- stage d chunk: 128x128 fp32 -> bf16 LDS, + mask chunk ----
    {
      const float4* src = (const float4*)(dmat + (size_t)b * SDN * HH + (size_t)tc * 128 * HH);
      #pragma unroll
      for (int it = 0; it < (128 * HH / 4) / 256; ++it) {  // 16 iters
        int idx4 = it * 256 + tid;
        float4 v = src[idx4];
        int idx = idx4 * 4;
        int r = idx >> 7, c = idx & 127;
        short4 o;
        o.x = f2bf(v.x); o.y = f2bf(v.y); o.z = f2bf(v.z); o.w = f2bf(v.w);
        *(short4*)&d_lds[r * HP + c] = o;
      }
      if (tid < 128) m_lds[tid] = mask[b * SDN + tc * 128 + tid];
    }
    __syncthreads();

    // ---- compute: 8 t-tiles of 16 per chunk ----
    #pragma unroll
    for (int tt = 0; tt < 8; ++tt) {
      acc_t acc = {0.f, 0.f, 0.f, 0.f};
      const short* bp = &d_lds[(tt * 16 + col) * HP + quad * 8];
      #pragma unroll
      for (int kc = 0; kc < 4; ++kc) {
        frag_t bfrag = *(const frag_t*)(bp + kc * 32);
        acc = __builtin_amdgcn_mfma_f32_16x16x32_bf16(afrag[kc], bfrag, acc, 0, 0, 0);
      }
      // C layout: col = lane&15 (t), row = quad*4 + reg (s). Mask is per-t.
      if (m_lds[tt * 16 + col]) {
        rmax0 = fmaxf(rmax0, acc[0]);
        rmax1 = fmaxf(rmax1, acc[1]);
        rmax2 = fmaxf(rmax2, acc[2]);
        rmax3 = fmaxf(rmax3, acc[3]);
      }
    }
    __syncthreads();   // protect d_lds before next stage
  }

  // ---- reduce: max over the 16 columns (lane bits 0..3) ----
  #pragma unroll
  for (int off = 1; off <= 8; off <<= 1) {
    rmax0 = fmaxf(rmax0, __shfl_xor(rmax0, off));
    rmax1 = fmaxf(rmax1, __shfl_xor(rmax1, off));
    rmax2 = fmaxf(rmax2, __shfl_xor(rmax2, off));
    rmax3 = fmaxf(rmax3, __shfl_xor(rmax3, off));
  }
  // each lane now has max_t for rows quad*4+{0..3}; sum rows, then add across quads
  float s = rmax0 + rmax1 + rmax2 + rmax3;
  s += __shfl_xor(s, 16);
  s += __shfl_xor(s, 32);
  if (lane == 0) red[wave] = s;
  __syncthreads();
  if (tid == 0)
    scores[a * (2 * BB) + side * BB + b] = red[0] + red[1] + red[2] + red[3];
}

// per-row: row_loss[a] = logsumexp(scores[a,:]) - scores[a,a]
__global__ __launch_bounds__(128)
void rowloss_kernel(const float* __restrict__ scores, float* __restrict__ row_loss) {
  const int a = blockIdx.x;
  const int tid = threadIdx.x;
  const int lane = tid & 63;
  const int wave = tid >> 6;
  __shared__ float sm[2], ss[2];
  float v = scores[a * 128 + tid];
  float mx = v;
  #pragma unroll
  for (int off = 32; off >= 1; off >>= 1) mx = fmaxf(mx, __shfl_xor(mx, off));
  if (lane == 0) sm[wave] = mx;
  __syncthreads();
  mx = fmaxf(sm[0], sm[1]);
  float e = __expf(v - mx);
  #pragma unroll
  for (int off = 32; off >= 1; off >>= 1) e += __shfl_xor(e, off);
  if (lane == 0) ss[wave] = e;
  __syncthreads();
  if (tid == 0) {
    float lse = mx + __logf(ss[0] + ss[1]);
    row_loss[a] = lse - scores[a * 128 + a];
  }
}

__global__ __launch_bounds__(64)
void final_kernel(const float* __restrict__ row_loss, float* __restrict__ out) {
  float v = row_loss[threadIdx.x];
  #pragma unroll
  for (int off = 32; off >= 1; off >>= 1) v += __shfl_xor(v, off);
  if (threadIdx.x == 0) out[0] = v * (1.0f / 64.0f);
}

extern "C" void kernel_launch(void* const* d_in, const int* in_sizes, int n_in,
                              void* d_out, int out_size, void* d_ws, size_t ws_size,
                              hipStream_t stream) {
  const float* q        = (const float*)d_in[0];
  const float* d_pos    = (const float*)d_in[1];
  const float* d_neg    = (const float*)d_in[2];
  const int*   mask_pos = (const int*)d_in[3];
  const int*   mask_neg = (const int*)d_in[4];

  float* scores   = (float*)d_ws;          // 64*128 fp32 = 32 KB
  float* row_loss = scores + 64 * 128;     // 64 fp32

  dim3 grid(BB /*a*/, BB /*b*/, 2 /*side*/);
  maxsim_kernel<<<grid, 256, 0, stream>>>(q, d_pos, d_neg, mask_pos, mask_neg, scores);
  rowloss_kernel<<<BB, 128, 0, stream>>>(scores, row_loss);
  final_kernel<<<1, 64, 0, stream>>>(row_loss, (float*)d_out);
}

// Round 2
// 182.193 us; speedup vs baseline: 1.2603x; 1.2603x over previous
//
#include <hip/hip_runtime.h>
#include <hip/hip_bf16.h>
#include <math.h>
#include <stdint.h>

// Problem: B=64, SQ=64, SD=512, H=128
#define BB 64
#define SQN 64
#define SDN 512
#define HH 128

typedef __attribute__((ext_vector_type(8))) short bf16x8;     // 4 VGPRs
typedef __attribute__((ext_vector_type(16))) float f32x16;    // 16 acc regs

__device__ __forceinline__ short f2bf(float f) {
  union { float f; unsigned u; } x; x.f = f;
  unsigned r = x.u + 0x7fffu + ((x.u >> 16) & 1u);   // RNE
  return (short)(r >> 16);
}

__device__ __forceinline__ void gl_lds16(const short* g, short* l) {
  __builtin_amdgcn_global_load_lds(
      (const __attribute__((address_space(1))) unsigned int*)g,
      (__attribute__((address_space(3))) unsigned int*)l, 16, 0, 0);
}

// ---- fp32 -> bf16 pre-convert for q, d_pos, d_neg (one pass) ----
__global__ __launch_bounds__(256)
void convert_kernel(const float* __restrict__ q, const float* __restrict__ dp,
                    const float* __restrict__ dn, short* __restrict__ oq,
                    short* __restrict__ odp, short* __restrict__ odn) {
  const int Q4 = (BB * SQN * HH) / 4;   // 131072
  const int D4 = (BB * SDN * HH) / 4;   // 1048576
  int i = blockIdx.x * 256 + threadIdx.x;      // total Q4 + 2*D4 = 2228224 (grid exact)
  const float4* src; short* dst; int off;
  if (i < Q4)           { src = (const float4*)q;  dst = oq;  off = i; }
  else if (i < Q4 + D4) { src = (const float4*)dp; dst = odp; off = i - Q4; }
  else                  { src = (const float4*)dn; dst = odn; off = i - Q4 - D4; }
  float4 v = src[off];
  short4 o; o.x = f2bf(v.x); o.y = f2bf(v.y); o.z = f2bf(v.z); o.w = f2bf(v.w);
  *(short4*)&dst[off * 4] = o;
}

// LDS layout (q_lds and d_lds): row-major 128 rows x 128 bf16 (256 B rows),
// 16B chunks XOR-swizzled: global chunk c of row r lives at chunk (c ^ (r&15)).
// Swizzle makes global_load_lds staging (lane-contiguous) AND ds_read_b128
// frag reads both conflict-free (2-way max = free per m136).

__global__ __launch_bounds__(256)
void maxsim_kernel(const short* __restrict__ qb,
                   const short* __restrict__ dbp,
                   const short* __restrict__ dbn,
                   const int* __restrict__ mask_pos,
                   const int* __restrict__ mask_neg,
                   float* __restrict__ scores) {
  const int agrp = blockIdx.x;   // 0..31 : a = agrp*2 + {0,1}
  const int b    = blockIdx.y;
  const int side = blockIdx.z;
  const short* db   = side ? dbn : dbp;
  const int*   mask = side ? mask_neg : mask_pos;

  __shared__ __align__(16) short q_lds[128 * 128];  // 2a x 64s, 32 KB
  __shared__ __align__(16) short d_lds[128 * 128];  // 128t chunk, 32 KB
  __shared__ int   m_lds[128];
  __shared__ float red[2 * 4 * 2 * 16];             // [a][wave][khalf-group][reg]

  const int tid = threadIdx.x;
  const int ln  = tid & 63;
  const int w   = tid >> 6;
  const int s_tile = w >> 1;   // 0/1 : s rows [s_tile*32, +32)
  const int t_half = w & 1;    // 0/1 : t-tiles {2*t_half, 2*t_half+1} per chunk
  const int l31 = ln & 31;
  const int kh  = ln >> 5;     // k-half for A/B frags

  // ---- stage q for both a's: 128 rows x 256 B via global_load_lds ----
  {
    const short* qsrc = qb + (size_t)(agrp * 2) * SQN * HH;
    #pragma unroll
    for (int it = 0; it < 8; ++it) {
      int f = it * 256 + tid;              // 16B-slot index
      int row = f >> 4;
      int c = (f & 15) ^ (row & 15);       // inverse swizzle -> global chunk
      gl_lds16(&qsrc[row * HH + c * 8], &q_lds[(it * 256 + w * 64) * 8]);
    }
  }
  __syncthreads();

  // ---- preload A-frags: [a][kc], row = a*64 + s_tile*32 + l31, k = kc*16 + kh*8 ----
  bf16x8 afrag[2][8];
  #pragma unroll
  for (int al = 0; al < 2; ++al) {
    int row = al * 64 + s_tile * 32 + l31;
    int rm = row & 15;
    #pragma unroll
    for (int kc = 0; kc < 8; ++kc) {
      int c = (kc * 2 + kh) ^ rm;
      afrag[al][kc] = *(const bf16x8*)&q_lds[row * HH + c * 8];
    }
  }

  float rmax[2][16];
  #pragma unroll
  for (int al = 0; al < 2; ++al)
    #pragma unroll
    for (int r = 0; r < 16; ++r) rmax[al][r] = -INFINITY;

  for (int tc = 0; tc < 4; ++tc) {
    // ---- stage d chunk (128 t x 128 k bf16) + mask chunk ----
    const short* dsrc = db + ((size_t)b * SDN + tc * 128) * HH;
    #pragma unroll
    for (int it = 0; it < 8; ++it) {
      int f = it * 256 + tid;
      int row = f >> 4;
      int c = (f & 15) ^ (row & 15);
      gl_lds16(&dsrc[row * HH + c * 8], &d_lds[(it * 256 + w * 64) * 8]);
    }
    if (tid < 128) m_lds[tid] = mask[b * SDN + tc * 128 + tid];
    __syncthreads();

    // ---- compute this wave's 2 t-tiles: 8 kc x 2 a MFMAs per tile ----
    #pragma unroll
    for (int tt2 = 0; tt2 < 2; ++tt2) {
      int tt = t_half * 2 + tt2;
      int trow = tt * 32 + l31;
      int tm = trow & 15;
      const short* bbase = &d_lds[trow * HH];
      f32x16 acc0 = {0,0,0,0,0,0,0,0,0,0,0,0,0,0,0,0};
      f32x16 acc1 = {0,0,0,0,0,0,0,0,0,0,0,0,0,0,0,0};
      #pragma unroll
      for (int kc = 0; kc < 8; ++kc) {
        int c = (kc * 2 + kh) ^ tm;
        bf16x8 bfrag = *(const bf16x8*)&bbase[c * 8];
        acc0 = __builtin_amdgcn_mfma_f32_32x32x16_bf16(afrag[0][kc], bfrag, acc0, 0, 0, 0);
        acc1 = __builtin_amdgcn_mfma_f32_32x32x16_bf16(afrag[1][kc], bfrag, acc1, 0, 0, 0);
      }
      // C layout: col = l31 (t), row = (reg&3) + 8*(reg>>2) + 4*kh (s within tile)
      bool mv = m_lds[trow] != 0;
      #pragma unroll
      for (int r = 0; r < 16; ++r) {
        rmax[0][r] = fmaxf(rmax[0][r], mv ? acc0[r] : -INFINITY);
        rmax[1][r] = fmaxf(rmax[1][r], mv ? acc1[r] : -INFINITY);
      }
    }
    __syncthreads();   // protect d_lds for next chunk
  }

  // ---- max over the 32 t-columns (lane bits 0..4) ----
  #pragma unroll
  for (int al = 0; al < 2; ++al)
    #pragma unroll
    for (int r = 0; r < 16; ++r) {
      float v = rmax[al][r];
      v = fmaxf(v, __shfl_xor(v, 1));
      v = fmaxf(v, __shfl_xor(v, 2));
      v = fmaxf(v, __shfl_xor(v, 4));
      v = fmaxf(v, __shfl_xor(v, 8));
      v = fmaxf(v, __shfl_xor(v, 16));
      rmax[al][r] = v;
    }
  if (l31 == 0) {
    #pragma unroll
    for (int al = 0; al < 2; ++al)
      #pragma unroll
      for (int r = 0; r < 16; ++r)
        red[((al * 4 + w) * 2 + kh) * 16 + r] = rmax[al][r];
  }
  __syncthreads();

  // ---- combine waves: max over t_half pairs, sum over s, write score ----
  if (tid < 128) {
    int al = tid >> 6;          // a_local (one wave per a)
    int s  = tid & 63;
    int st = s >> 5;            // s_tile
    int r32 = s & 31;
    int g   = (r32 >> 2) & 1;   // kh group
    int reg = (r32 & 3) | ((r32 >> 3) << 2);
    int w0 = st * 2;
    float v = fmaxf(red[((al * 4 + w0)     * 2 + g) * 16 + reg],
                    red[((al * 4 + w0 + 1) * 2 + g) * 16 + reg]);
    v += __shfl_xor(v, 1);  v += __shfl_xor(v, 2);  v += __shfl_xor(v, 4);
    v += __shfl_xor(v, 8);  v += __shfl_xor(v, 16); v += __shfl_xor(v, 32);
    if ((tid & 63) == 0)
      scores[(size_t)(agrp * 2 + al) * (2 * BB) + side * BB + b] = v;
  }
}

// per-row: row_loss[a] = logsumexp(scores[a,:]) - scores[a,a]
__global__ __launch_bounds__(128)
void rowloss_kernel(const float* __restrict__ scores, float* __restrict__ row_loss) {
  const int a = blockIdx.x;
  const int tid = threadIdx.x;
  const int lane = tid & 63;
  const int wave = tid >> 6;
  __shared__ float sm[2], ss[2];
  float v = scores[a * 128 + tid];
  float mx = v;
  #pragma unroll
  for (int off = 32; off >= 1; off >>= 1) mx = fmaxf(mx, __shfl_xor(mx, off));
  if (lane == 0) sm[wave] = mx;
  __syncthreads();
  mx = fmaxf(sm[0], sm[1]);
  float e = __expf(v - mx);
  #pragma unroll
  for (int off = 32; off >= 1; off >>= 1) e += __shfl_xor(e, off);
  if (lane == 0) ss[wave] = e;
  __syncthreads();
  if (tid == 0) {
    float lse = mx + __logf(ss[0] + ss[1]);
    row_loss[a] = lse - scores[a * 128 + a];
  }
}

__global__ __launch_bounds__(64)
void final_kernel(const float* __restrict__ row_loss, float* __restrict__ out) {
  float v = row_loss[threadIdx.x];
  #pragma unroll
  for (int off = 32; off >= 1; off >>= 1) v += __shfl_xor(v, off);
  if (threadIdx.x == 0) out[0] = v * (1.0f / 64.0f);
}

extern "C" void kernel_launch(void* const* d_in, const int* in_sizes, int n_in,
                              void* d_out, int out_size, void* d_ws, size_t ws_size,
                              hipStream_t stream) {
  const float* q        = (const float*)d_in[0];
  const float* d_pos    = (const float*)d_in[1];
  const float* d_neg    = (const float*)d_in[2];
  const int*   mask_pos = (const int*)d_in[3];
  const int*   mask_neg = (const int*)d_in[4];

  // ws layout (bf16 staging + reductions): needs ~17.9 MB
  short* q_bf  = (short*)d_ws;                       // 524288 shorts
  short* dp_bf = q_bf + (size_t)BB * SQN * HH;       // 4194304 shorts
  short* dn_bf = dp_bf + (size_t)BB * SDN * HH;      // 4194304 shorts
  float* scores   = (float*)(dn_bf + (size_t)BB * SDN * HH);   // 8192 floats
  float* row_loss = scores + BB * 2 * BB;

  const int total4 = (BB * SQN * HH + 2 * BB * SDN * HH) / 4;  // 2228224
  convert_kernel<<<total4 / 256, 256, 0, stream>>>(q, d_pos, d_neg, q_bf, dp_bf, dn_bf);

  dim3 grid(BB / 2 /*a-groups*/, BB /*b*/, 2 /*side*/);
  maxsim_kernel<<<grid, 256, 0, stream>>>(q_bf, dp_bf, dn_bf, mask_pos, mask_neg, scores);

  rowloss_kernel<<<BB, 128, 0, stream>>>(scores, row_loss);
  final_kernel<<<1, 64, 0, stream>>>(row_loss, (float*)d_out);
}